// Round 3
// baseline (65.689 us; speedup 1.0000x reference)
//
#include <hip/hip_runtime.h>
#include <hip/hip_bf16.h>

#define SS 32
#define EE 64
#define DD 256
#define LL 5

typedef unsigned int uint32;

static __device__ __forceinline__ ushort f2bf(float f) {
    uint32 u = __float_as_uint(f);
    uint32 r = (u + 0x7FFFu + ((u >> 16) & 1u)) >> 16;   // RNE
    return (ushort)r;
}
static __device__ __forceinline__ float bf2f(ushort h) {
    return __uint_as_float(((uint32)h) << 16);
}

// ws layout (f32 units):
//   pa   = ws + 0      (1280)   pb  = ws + 1280 (1280)
//   pa2  = ws + 2560   (5)      pb2 = ws + 2565 (5)    cvec = ws + 2570 (5)
//   xself= ws + 4096   (524288)
//   xw   = (ushort*)(ws + 528384)  (524288 bf16)
//   wt   = ws + 790528 (655360)  [s][k][u][v]
//   da   = ws + 1445888 (51200)  db = ws + 1497088 (51200)

// ================= K_A: GEMM + context-distance stream + setup =============
// blocks 0..255   : GEMM  x@W (bf16 out) and x@Wself (f32 out), 8 rows each
// blocks 256..2303: per-(s,u) context slab -> w weights
// block  2304     : proto means / norms / cvec
// launch_bounds(256,2): 2 blocks/CU target -> up to ~256 VGPR, NO SPILLS
// (R2 post-mortem: default heuristic squeezed to 48 VGPR and spilled the
//  GEMM accumulators -> 75us scratch-bound kernel).
__global__ __launch_bounds__(256, 2) void kA(
    const float* __restrict__ sup_entities, const float* __restrict__ sup_context,
    const float* __restrict__ x, const float* __restrict__ context,
    const float* __restrict__ W, const float* __restrict__ Wself,
    const int* __restrict__ counts, float* __restrict__ ws) {

    __shared__ float smem[8192];   // 32 KB, repurposed per branch
    int bx = blockIdx.x;
    int t = threadIdx.x, lane = t & 63, wv = t >> 6;

    float* xself = ws + 4096;
    ushort* xw = (ushort*)(ws + 528384);
    float* wt = ws + 790528;

    if (bx < 256) {
        // ---------------- GEMM branch ----------------
        int row0 = bx * 8;
        float xreg[8];
        const float* xbase = x + row0 * DD + wv * 64 + lane;
#pragma unroll
        for (int r = 0; r < 8; r++) xreg[r] = xbase[r * DD];

        float4 accW[8], accS[8];
#pragma unroll
        for (int r = 0; r < 8; r++) {
            accW[r] = make_float4(0.f, 0.f, 0.f, 0.f);
            accS[r] = make_float4(0.f, 0.f, 0.f, 0.f);
        }
        const float4* Wp  = ((const float4*)W) + lane;
        const float4* Wsp = ((const float4*)Wself) + lane;
#pragma unroll 2
        for (int i = 0; i < 64; i++) {
            int kk = wv * 64 + i;
            float4 w4  = Wp[kk * 64];
            float4 ws4 = Wsp[kk * 64];
#pragma unroll
            for (int r = 0; r < 8; r++) {
                float xs = __uint_as_float(
                    (uint32)__builtin_amdgcn_readlane((int)__float_as_uint(xreg[r]), i));
                accW[r].x = fmaf(xs, w4.x, accW[r].x);
                accW[r].y = fmaf(xs, w4.y, accW[r].y);
                accW[r].z = fmaf(xs, w4.z, accW[r].z);
                accW[r].w = fmaf(xs, w4.w, accW[r].w);
                accS[r].x = fmaf(xs, ws4.x, accS[r].x);
                accS[r].y = fmaf(xs, ws4.y, accS[r].y);
                accS[r].z = fmaf(xs, ws4.z, accS[r].z);
                accS[r].w = fmaf(xs, ws4.w, accS[r].w);
            }
        }
        float4* redbuf = (float4*)smem;   // [4][8][64]
#pragma unroll
        for (int r = 0; r < 8; r++) redbuf[(wv * 8 + r) * 64 + lane] = accS[r];
        __syncthreads();
        {
            int r = t >> 5;
#pragma unroll
            for (int f = 0; f < 2; f++) {
                int l4 = (t & 31) + 32 * f;
                float4 a = redbuf[(0 * 8 + r) * 64 + l4], b = redbuf[(1 * 8 + r) * 64 + l4];
                float4 c = redbuf[(2 * 8 + r) * 64 + l4], d = redbuf[(3 * 8 + r) * 64 + l4];
                float4 s4 = make_float4(a.x + b.x + c.x + d.x, a.y + b.y + c.y + d.y,
                                        a.z + b.z + c.z + d.z, a.w + b.w + c.w + d.w);
                *(float4*)&xself[(row0 + r) * DD + l4 * 4] = s4;
            }
        }
        __syncthreads();
#pragma unroll
        for (int r = 0; r < 8; r++) redbuf[(wv * 8 + r) * 64 + lane] = accW[r];
        __syncthreads();
        {
            int r = t >> 5;
#pragma unroll
            for (int f = 0; f < 2; f++) {
                int l4 = (t & 31) + 32 * f;
                float4 a = redbuf[(0 * 8 + r) * 64 + l4], b = redbuf[(1 * 8 + r) * 64 + l4];
                float4 c = redbuf[(2 * 8 + r) * 64 + l4], d = redbuf[(3 * 8 + r) * 64 + l4];
                float4 s4 = make_float4(a.x + b.x + c.x + d.x, a.y + b.y + c.y + d.y,
                                        a.z + b.z + c.z + d.z, a.w + b.w + c.w + d.w);
                ushort4 h;
                h.x = f2bf(s4.x); h.y = f2bf(s4.y); h.z = f2bf(s4.z); h.w = f2bf(s4.w);
                *(ushort4*)&xw[(row0 + r) * DD + l4 * 4] = h;
            }
        }
    } else if (bx < 2304) {
        // ---------------- context stream branch ----------------
        int bs = bx - 256;
        int s = bs >> 6, u = bs & 63;
        float* cc_l  = smem;          // [5][256]
        float* cc2_l = smem + 1280;   // [5]
        float* wbuf  = smem + 1288;   // [5][64]

        for (int i = t; i < 1280; i += 256) {
            int k = i >> 8, d = i & 255;
            float sum = 0.f;
#pragma unroll
            for (int j = 0; j < 5; j++) sum += sup_context[(k * 5 + j) * DD + d];
            cc_l[i] = sum * 0.2f;
        }
        __syncthreads();
        if (t < 80) {
            int k = t >> 4, gl = t & 15;
            float p = 0.f;
#pragma unroll
            for (int j = 0; j < 16; j++) { float v = cc_l[k * 256 + gl * 16 + j]; p = fmaf(v, v, p); }
#pragma unroll
            for (int off = 1; off < 16; off <<= 1) p += __shfl_xor(p, off);
            if (gl == 0) cc2_l[k] = p;
        }
        __syncthreads();

        int g = lane >> 4, gl = lane & 15;
        // protos + norms into REGISTERS (R2 had these as per-pass LDS reads:
        // 80 ds_read_b128/thread — ~13us of chip-wide LDS traffic)
        float4 cc[5][4];
        float cc2r[5];
#pragma unroll
        for (int k = 0; k < 5; k++) {
#pragma unroll
            for (int j = 0; j < 4; j++)
                cc[k][j] = *(const float4*)&cc_l[k * 256 + j * 64 + gl * 4];
            cc2r[k] = cc2_l[k];
        }

        const float* base = context + ((size_t)bs) * (EE * DD);
        // issue ALL 16 global loads (fully static indices -> registers, deep MLP)
        float4 ld[4][4];
#pragma unroll
        for (int p = 0; p < 4; p++) {
            int v = p * 16 + wv * 4 + g;
            const float* row = base + v * DD;
#pragma unroll
            for (int j = 0; j < 4; j++) ld[p][j] = *(const float4*)&row[j * 64 + gl * 4];
        }
#pragma unroll
        for (int p = 0; p < 4; p++) {
            int v = p * 16 + wv * 4 + g;
            float cn2 = 0.f;
            float cr[5] = {0.f, 0.f, 0.f, 0.f, 0.f};
#pragma unroll
            for (int j = 0; j < 4; j++) {
                float4 c4 = ld[p][j];
                cn2 = fmaf(c4.x, c4.x, fmaf(c4.y, c4.y, fmaf(c4.z, c4.z, fmaf(c4.w, c4.w, cn2))));
#pragma unroll
                for (int k = 0; k < 5; k++) {
                    float4 pp = cc[k][j];
                    cr[k] = fmaf(c4.x, pp.x, fmaf(c4.y, pp.y, fmaf(c4.z, pp.z, fmaf(c4.w, pp.w, cr[k]))));
                }
            }
#pragma unroll
            for (int off = 1; off < 16; off <<= 1) {
                cn2 += __shfl_xor(cn2, off);
#pragma unroll
                for (int k = 0; k < 5; k++) cr[k] += __shfl_xor(cr[k], off);
            }
            if (gl == 0) {
#pragma unroll
                for (int k = 0; k < 5; k++) {
                    float d2 = cn2 - 2.f * cr[k] + cc2r[k];
                    wbuf[k * 64 + v] = (u == v) ? 0.f : 1.f / fmaxf(d2, 1e-8f);
                }
            }
        }
        __syncthreads();
        for (int i = t; i < 320; i += 256) {
            int k = i >> 6, v = i & 63;
            wt[(((size_t)s * 5 + k) * 64 + u) * 64 + v] = wbuf[k * 64 + v];
        }
    } else {
        // ---------------- setup branch ----------------
        for (int i = t; i < 2560; i += 256) {
            int k = i >> 9, d = i & 511;
            float s = 0.f;
#pragma unroll
            for (int j = 0; j < 5; j++) s += sup_entities[(k * 5 + j) * 512 + d];
            float m = s * 0.2f;
            if (d < 256) ws[k * 256 + d] = m;
            else         ws[1280 + k * 256 + (d - 256)] = m;
        }
        __syncthreads();
        if (t < 10) {
            const float* p = ws + ((t >= 5) ? 1280 : 0) + (t % 5) * 256;
            float s = 0.f;
            for (int d = 0; d < 256; d++) s = fmaf(p[d], p[d], s);
            ws[2560 + t] = s;   // pa2[0..5), pb2[5..10)
        }
        if (t == 0) {
            float cnt[5], tot = 0.f;
#pragma unroll
            for (int k = 0; k < 5; k++) { cnt[k] = (float)counts[k] + 1.0f; tot += cnt[k]; }
#pragma unroll
            for (int k = 0; k < 5; k++) ws[2570 + k] = cnt[k] / (tot - cnt[k]);
        }
    }
}

// ================= K_B: out = xself + w.xW  fused with distance dots =======
// 512 blocks = (s, vgroup of 4 v). 4 waves: wave handles 1 v x 5 k.
__global__ __launch_bounds__(256, 2) void kB(const float* __restrict__ ws) {
    const ushort* xw = (const ushort*)(ws + 528384);
    const float* xself = ws + 4096;
    const float* wt = ws + 790528;
    float* da = (float*)(ws + 1445888);
    float* db = (float*)(ws + 1497088);

    int bx = blockIdx.x;
    int s = bx >> 4, vg = bx & 15;
    int t = threadIdx.x, lane = t & 63, wv = t >> 6;

    __shared__ ushort xw_l[64][256];   // 32 KB
    __shared__ float  w_l[5][64][4];   // 5 KB

    {
        const uint4* src = (const uint4*)(xw + (size_t)s * (EE * DD));
        uint4* dst = (uint4*)&xw_l[0][0];
#pragma unroll
        for (int j = 0; j < 8; j++) dst[j * 256 + t] = src[j * 256 + t];
    }
    for (int i = t; i < 320; i += 256) {
        int k = i >> 6, u = i & 63;
        *(float4*)&w_l[k][u][0] =
            *(const float4*)&wt[(((size_t)s * 5 + k) * 64 + u) * 64 + vg * 4];
    }
    __syncthreads();

    int v = vg * 4 + wv;
    float4 acc[5];
    {
        float4 xs = *(const float4*)&xself[((size_t)s * 64 + v) * DD + lane * 4];
#pragma unroll
        for (int k = 0; k < 5; k++) acc[k] = xs;
    }

#pragma unroll 4
    for (int u = 0; u < 64; u++) {
        ushort4 h4 = *(const ushort4*)&xw_l[u][lane * 4];
        float4 xv = make_float4(bf2f(h4.x), bf2f(h4.y), bf2f(h4.z), bf2f(h4.w));
#pragma unroll
        for (int k = 0; k < 5; k++) {
            float wk = w_l[k][u][wv];
            acc[k].x = fmaf(wk, xv.x, acc[k].x);
            acc[k].y = fmaf(wk, xv.y, acc[k].y);
            acc[k].z = fmaf(wk, xv.z, acc[k].z);
            acc[k].w = fmaf(wk, xv.w, acc[k].w);
        }
    }

    // epilogue: 11 dot-reductions per k
    float4 pA[5], pB[5];
#pragma unroll
    for (int n = 0; n < 5; n++) {
        pA[n] = *(const float4*)&ws[n * 256 + lane * 4];
        pB[n] = *(const float4*)&ws[1280 + n * 256 + lane * 4];
    }
    float pa2r[5], pb2r[5];
#pragma unroll
    for (int n = 0; n < 5; n++) { pa2r[n] = ws[2560 + n]; pb2r[n] = ws[2565 + n]; }

#pragma unroll
    for (int k = 0; k < 5; k++) {
        float4 o = acc[k];
        float r[11];
        r[0] = fmaf(o.x, o.x, fmaf(o.y, o.y, fmaf(o.z, o.z, o.w * o.w)));
#pragma unroll
        for (int n = 0; n < 5; n++) {
            float4 p = pA[n];
            r[1 + n] = fmaf(o.x, p.x, fmaf(o.y, p.y, fmaf(o.z, p.z, o.w * p.w)));
            float4 q = pB[n];
            r[6 + n] = fmaf(o.x, q.x, fmaf(o.y, q.y, fmaf(o.z, q.z, o.w * q.w)));
        }
#pragma unroll
        for (int off = 1; off < 64; off <<= 1) {
#pragma unroll
            for (int q = 0; q < 11; q++) r[q] += __shfl_xor(r[q], off);
        }
        if (lane == 0) {
            size_t idx = (((size_t)s * 5 + k) * 64 + v) * 5;
#pragma unroll
            for (int n = 0; n < 5; n++) {
                da[idx + n] = r[0] - 2.f * r[1 + n] + pa2r[n];
                db[idx + n] = r[0] - 2.f * r[6 + n] + pb2r[n];
            }
        }
    }
}

// ================= K_C: logits + softmax + coalesced store ==================
__global__ __launch_bounds__(320) void kC(const float* __restrict__ ws,
                                          float* __restrict__ out) {
    const float* da = ws + 1445888;
    const float* db = ws + 1497088;
    int bx = blockIdx.x;
    int s = bx >> 6, v1 = bx & 63;
    int t = threadIdx.x;
    int v2 = t / 5, k = t - v2 * 5;

    __shared__ float ob[1600];
    __shared__ float cvs[5];
    if (t < 5) cvs[t] = ws[2570 + t];

    const float* dap = da + (((size_t)s * 5 + k) * 64 + v1) * 5;
    const float* dbp = db + (((size_t)s * 5 + k) * 64 + v2) * 5;
    float l0[5];
#pragma unroll
    for (int n = 0; n < 5; n++) l0[n] = dap[n] + dbp[n];
    __syncthreads();
    float m = -3.4e38f;
#pragma unroll
    for (int n = 0; n < 5; n++) { l0[n] += cvs[n]; m = fmaxf(m, l0[n]); }
    float e[5], sum = 0.f;
#pragma unroll
    for (int n = 0; n < 5; n++) { e[n] = __expf(l0[n] - m); sum += e[n]; }
    float r = 1.f / sum;
#pragma unroll
    for (int n = 0; n < 5; n++) ob[t * 5 + n] = e[n] * r;
    __syncthreads();

    const float4* ob4 = (const float4*)ob;
    float4* op = (float4*)(out + (size_t)bx * 1600);
    for (int i = t; i < 400; i += 320) op[i] = ob4[i];
}

// ---------------- launch ----------------------------------------------------
extern "C" void kernel_launch(void* const* d_in, const int* in_sizes, int n_in,
                              void* d_out, int out_size, void* d_ws, size_t ws_size,
                              hipStream_t stream) {
    const float* sup_entities = (const float*)d_in[0];
    const float* sup_context  = (const float*)d_in[1];
    const float* x            = (const float*)d_in[2];
    const float* context      = (const float*)d_in[3];
    const float* W            = (const float*)d_in[4];
    const float* Wself        = (const float*)d_in[5];
    const int*   counts       = (const int*)d_in[6];
    float* out = (float*)d_out;
    float* ws = (float*)d_ws;

    kA<<<2305, 256, 0, stream>>>(sup_entities, sup_context, x, context, W, Wself, counts, ws);
    kB<<<512, 256, 0, stream>>>(ws);
    kC<<<SS * EE, 320, 0, stream>>>(ws, out);
}